// Round 7
// baseline (356.997 us; speedup 1.0000x reference)
//
#include <hip/hip_runtime.h>
#include <hip/hip_bf16.h>
#include <stdint.h>

typedef unsigned short u16;
typedef unsigned int u32;
typedef __bf16 bf16x8 __attribute__((ext_vector_type(8)));
typedef float f32x4 __attribute__((ext_vector_type(4)));

__device__ __forceinline__ u16 f2bf(float v) {
  union { __hip_bfloat16 b; u16 u; } c; c.b = __float2bfloat16(v); return c.u;
}

__device__ __forceinline__ uint4 pack8(float4 lo, float4 hi) {
  uint4 q;
  q.x = (u32)f2bf(lo.x) | ((u32)f2bf(lo.y) << 16);
  q.y = (u32)f2bf(lo.z) | ((u32)f2bf(lo.w) << 16);
  q.z = (u32)f2bf(hi.x) | ((u32)f2bf(hi.y) << 16);
  q.w = (u32)f2bf(hi.z) | ((u32)f2bf(hi.w) << 16);
  return q;
}

// ---------------- transpose + fp32->bf16 convert, 2x 1024x1024 ------------
__global__ void transpose1024_cvt2(const float* __restrict__ in0, u16* __restrict__ out0,
                                   const float* __restrict__ in1, u16* __restrict__ out1) {
  const float* in = blockIdx.z ? in1 : in0;
  u16* out = blockIdx.z ? out1 : out0;
  __shared__ u16 tile[32][33];
  int tx = threadIdx.x, ty = threadIdx.y;            // block (32,8)
  int c0 = blockIdx.x * 32, r0 = blockIdx.y * 32;
#pragma unroll
  for (int i = 0; i < 32; i += 8)
    tile[ty + i][tx] = f2bf(in[(size_t)(r0 + ty + i) * 1024 + c0 + tx]);
  __syncthreads();
#pragma unroll
  for (int i = 0; i < 32; i += 8)
    out[(size_t)(c0 + ty + i) * 1024 + r0 + tx] = tile[tx][ty + i];
}

// ---------------- build Vt[b][h][d][j] = mask[b][j] ? 0 : w[b,j][h*64+d] --
// 32x32 tile transpose. grid: (j-tiles=64, d-tiles=2, bh=32), block (32,8)
__global__ void scale_transpose_v(const u16* __restrict__ w, const int* __restrict__ mask,
                                  u16* __restrict__ Vt) {
  __shared__ u16 tile[32][33];
  const int tx = threadIdx.x, ty = threadIdx.y;
  const int j0 = blockIdx.x * 32, d0 = blockIdx.y * 32;
  const int bh = blockIdx.z, b = bh >> 4, hc = (bh & 15) * 64;
#pragma unroll
  for (int i = 0; i < 32; i += 8) {
    int j = j0 + ty + i;
    u16 v = w[(size_t)(b * 2048 + j) * 1024 + hc + d0 + tx];
    tile[ty + i][tx] = mask[b * 2048 + j] ? (u16)0 : v;
  }
  __syncthreads();
#pragma unroll
  for (int i = 0; i < 32; i += 8)
    Vt[((size_t)bh * 64 + d0 + ty + i) * 2048 + j0 + tx] = tile[tx][ty + i];
}

// ---------------- GEMM: C(MxN) = A(MxK) * BT(NxK)^T  [+bias] --------------
// 128x64 tile / 256 threads / BK=32 (unchanged from round 6).
template<bool A_F32, bool OUT_F32>
__launch_bounds__(256)
__global__ void gemm_bt(const void* __restrict__ Ap, const u16* __restrict__ BT,
                        void* __restrict__ Cp, const float* __restrict__ bias,
                        int M, int N, int K) {
  __shared__ __align__(16) u16 As[128 * 32];
  __shared__ __align__(16) u16 Bs[64 * 32];
  const int t = threadIdx.x;
  const int lane = t & 63, wave = t >> 6;
  const int m0 = blockIdx.x * 128, n0 = blockIdx.y * 64;
  const int wm = (wave & 1) * 64, wn = (wave >> 1) * 32;
  const int lrow = lane & 15, quad = lane >> 4;

  f32x4 acc[4][2] = {};

  const int ar = t >> 2, ac = (t & 3) * 8;
  const size_t aBase = (size_t)(m0 + ar) * K + ac;
  const u16* gB = BT + (size_t)(n0 + ar) * K + ac;

  for (int k0 = 0; k0 < K; k0 += 32) {
    uint4 a0, a1;
    if (A_F32) {
      const float* p0 = (const float*)Ap + aBase + k0;
      const float* p1 = (const float*)Ap + aBase + k0 + (size_t)64 * K;
      a0 = pack8(*(const float4*)p0, *(const float4*)(p0 + 4));
      a1 = pack8(*(const float4*)p1, *(const float4*)(p1 + 4));
    } else {
      a0 = *(const uint4*)((const u16*)Ap + aBase + k0);
      a1 = *(const uint4*)((const u16*)Ap + aBase + k0 + (size_t)64 * K);
    }
    uint4 b0 = *(const uint4*)(gB + k0);
    __syncthreads();
    *(uint4*)&As[t * 8]        = a0;
    *(uint4*)&As[t * 8 + 2048] = a1;
    *(uint4*)&Bs[t * 8]        = b0;
    __syncthreads();

    bf16x8 af[4], bfr[2];
#pragma unroll
    for (int i = 0; i < 4; i++)
      af[i] = *(const bf16x8*)&As[(wm + i * 16 + lrow) * 32 + quad * 8];
#pragma unroll
    for (int j = 0; j < 2; j++)
      bfr[j] = *(const bf16x8*)&Bs[(wn + j * 16 + lrow) * 32 + quad * 8];
#pragma unroll
    for (int i = 0; i < 4; i++)
#pragma unroll
      for (int j = 0; j < 2; j++)
        acc[i][j] = __builtin_amdgcn_mfma_f32_16x16x32_bf16(af[i], bfr[j], acc[i][j], 0, 0, 0);
  }

  float bv[2];
#pragma unroll
  for (int j = 0; j < 2; j++)
    bv[j] = bias ? bias[n0 + wn + j * 16 + lrow] : 0.f;

#pragma unroll
  for (int i = 0; i < 4; i++) {
#pragma unroll
    for (int r = 0; r < 4; r++) {
      int row = m0 + wm + i * 16 + quad * 4 + r;
#pragma unroll
      for (int j = 0; j < 2; j++) {
        size_t ci = (size_t)row * N + n0 + wn + j * 16 + lrow;
        float v = acc[i][j][r] + bv[j];
        if (OUT_F32) ((float*)Cp)[ci] = v;
        else ((u16*)Cp)[ci] = f2bf(v);
      }
    }
  }
}

// ---------------- fused attention per (b,h), 64 q-rows per block ----------
// BARRIER-FREE: K frags direct from w (L2), V frags direct from pre-masked,
// pre-transposed Vt (already in MFMA-B layout). LDS only for per-wave P
// round-trip (C-layout -> A-layout). Fixed-max softmax, denom over ALL cols;
// masking is folded into Vt (mask values are exactly {0,1} -> select).
#define SV 72
#define C1 0.18033688f      // 0.125 * log2(e)
#define C2 -28.853901f      // -20 * log2(e)
__launch_bounds__(256)
__global__ void attn_kernel(const u16* __restrict__ w, const u16* __restrict__ Vt,
                            u16* __restrict__ y) {
  __shared__ __align__(16) u16 P[4][16 * SV];      // per-wave P: [16 q][64 key]
  const int t = threadIdx.x, lane = t & 63, wave = t >> 6;
  const int lrow = lane & 15, quad = lane >> 4;
  const int bh = blockIdx.y, b = bh >> 4, h = bh & 15;
  const int q0 = blockIdx.x * 64;
  const size_t rowb = (size_t)b * 2048;
  const int hc = h * 64;
  u16* Pw = P[wave];
  const u16* vbase = Vt + (size_t)bh * 64 * 2048;

  // Q fragments: 16 rows x 64 k, in regs for whole kernel
  bf16x8 qf0, qf1;
  {
    const size_t qrow = rowb + q0 + wave * 16 + lrow;
    qf0 = *(const bf16x8*)&w[qrow * 1024 + hc + quad * 8];
    qf1 = *(const bf16x8*)&w[qrow * 1024 + hc + 32 + quad * 8];
  }

  f32x4 o[4] = {};
  float lrun[4] = {0.f, 0.f, 0.f, 0.f};

  for (int j0 = 0; j0 < 2048; j0 += 64) {
    // ---- 1. issue V frag loads first (consumed last, ~400 cyc away)
    bf16x8 vb[4][2];
#pragma unroll
    for (int dt = 0; dt < 4; dt++) {
      const u16* vp = &vbase[(size_t)(dt * 16 + lrow) * 2048 + j0 + quad * 8];
      vb[dt][0] = *(const bf16x8*)vp;
      vb[dt][1] = *(const bf16x8*)(vp + 32);
    }

    // ---- 2. K frags + QK^T
    f32x4 st[4];
#pragma unroll
    for (int jt = 0; jt < 4; jt++) {
      const u16* kp = &w[(rowb + j0 + jt * 16 + lrow) * 1024 + hc + quad * 8];
      bf16x8 kf0 = *(const bf16x8*)kp;
      bf16x8 kf1 = *(const bf16x8*)(kp + 32);
      f32x4 z = {};
      z = __builtin_amdgcn_mfma_f32_16x16x32_bf16(qf0, kf0, z, 0, 0, 0);
      z = __builtin_amdgcn_mfma_f32_16x16x32_bf16(qf1, kf1, z, 0, 0, 0);
      st[jt] = z;
    }

    // ---- 3. softmax (fixed max, folded scale); no mask here (it's in Vt)
#pragma unroll
    for (int jt = 0; jt < 4; jt++) {
#pragma unroll
      for (int r = 0; r < 4; r++) {
        float e = exp2f(fmaf(st[jt][r], C1, C2));
        lrun[r] += e;                               // denominator: UNmasked
        Pw[(quad * 4 + r) * SV + jt * 16 + lrow] = f2bf(e);
      }
    }

    // ---- 4. P·V (P round-trip same-wave; compiler inserts lgkmcnt waits)
    bf16x8 pa0 = *(const bf16x8*)&Pw[lrow * SV + quad * 8];
    bf16x8 pa1 = *(const bf16x8*)&Pw[lrow * SV + 32 + quad * 8];
#pragma unroll
    for (int dt = 0; dt < 4; dt++) {
      o[dt] = __builtin_amdgcn_mfma_f32_16x16x32_bf16(pa0, vb[dt][0], o[dt], 0, 0, 0);
      o[dt] = __builtin_amdgcn_mfma_f32_16x16x32_bf16(pa1, vb[dt][1], o[dt], 0, 0, 0);
    }
  }

  // ---- finalize: reduce denominator across 16-lane group, divide, store
#pragma unroll
  for (int r = 0; r < 4; r++) {
    float l = lrun[r];
#pragma unroll
    for (int s = 8; s >= 1; s >>= 1)
      l += __shfl_xor(l, s, 64);
    float inv = 1.f / l;
    const size_t orow = rowb + q0 + wave * 16 + quad * 4 + r;
#pragma unroll
    for (int dt = 0; dt < 4; dt++)
      y[orow * 1024 + hc + dt * 16 + lrow] = f2bf(o[dt][r] * inv);
  }
}

// --------------------------------------------------------------------------
extern "C" void kernel_launch(void* const* d_in, const int* in_sizes, int n_in,
                              void* d_out, int out_size, void* d_ws, size_t ws_size,
                              hipStream_t stream) {
  const float* x    = (const float*)d_in[0];  // (2,2048,1024) fp32
  const int* mask   = (const int*)d_in[1];    // (2,2048) int32
  const float* Wqkv = (const float*)d_in[2];  // (1024,1024) fp32
  const float* Wout = (const float*)d_in[3];  // (1024,1024) fp32
  const float* bout = (const float*)d_in[4];  // (1024,) fp32
  float* out = (float*)d_out;                 // (2,2048,1024) fp32

  u16* w     = (u16*)d_ws;                 // 4096*1024 bf16   (8 MB)
  u16* y     = w + 4096 * 1024;            // 4096*1024 bf16   (8 MB)
  u16* WqkvT = y + 4096 * 1024;            // 1024*1024 bf16   (2 MB)
  u16* WoutT = WqkvT + 1024 * 1024;        // 1024*1024 bf16   (2 MB)
  u16* Vt    = WoutT + 1024 * 1024;        // 32*64*2048 bf16  (8 MB)

  transpose1024_cvt2<<<dim3(32, 32, 2), dim3(32, 8), 0, stream>>>(Wqkv, WqkvT, Wout, WoutT);
  gemm_bt<true, false><<<dim3(32, 16), 256, 0, stream>>>(x, WqkvT, w, nullptr, 4096, 1024, 1024);
  scale_transpose_v<<<dim3(64, 2, 32), dim3(32, 8), 0, stream>>>(w, mask, Vt);
  attn_kernel<<<dim3(32, 32), 256, 0, stream>>>(w, Vt, y);
  gemm_bt<false, true><<<dim3(32, 16), 256, 0, stream>>>(y, WoutT, out, bout, 4096, 1024, 1024);
}

// Round 8
// 203.890 us; speedup vs baseline: 1.7509x; 1.7509x over previous
//
#include <hip/hip_runtime.h>
#include <hip/hip_bf16.h>
#include <stdint.h>

typedef unsigned short u16;
typedef unsigned int u32;
typedef __bf16 bf16x8 __attribute__((ext_vector_type(8)));
typedef float f32x4 __attribute__((ext_vector_type(4)));

__device__ __forceinline__ u16 f2bf(float v) {
  union { __hip_bfloat16 b; u16 u; } c; c.b = __float2bfloat16(v); return c.u;
}

__device__ __forceinline__ uint4 pack8(float4 lo, float4 hi) {
  uint4 q;
  q.x = (u32)f2bf(lo.x) | ((u32)f2bf(lo.y) << 16);
  q.y = (u32)f2bf(lo.z) | ((u32)f2bf(lo.w) << 16);
  q.z = (u32)f2bf(hi.x) | ((u32)f2bf(hi.y) << 16);
  q.w = (u32)f2bf(hi.z) | ((u32)f2bf(hi.w) << 16);
  return q;
}

// ---------------- transpose + fp32->bf16 convert, 2x 1024x1024 ------------
__global__ void transpose1024_cvt2(const float* __restrict__ in0, u16* __restrict__ out0,
                                   const float* __restrict__ in1, u16* __restrict__ out1) {
  const float* in = blockIdx.z ? in1 : in0;
  u16* out = blockIdx.z ? out1 : out0;
  __shared__ u16 tile[32][33];
  int tx = threadIdx.x, ty = threadIdx.y;            // block (32,8)
  int c0 = blockIdx.x * 32, r0 = blockIdx.y * 32;
#pragma unroll
  for (int i = 0; i < 32; i += 8)
    tile[ty + i][tx] = f2bf(in[(size_t)(r0 + ty + i) * 1024 + c0 + tx]);
  __syncthreads();
#pragma unroll
  for (int i = 0; i < 32; i += 8)
    out[(size_t)(c0 + ty + i) * 1024 + r0 + tx] = tile[tx][ty + i];
}

// ---------------- build Vt[b][h][d][j] = mask[b][j] ? 0 : w[b,j][h*64+d] --
// 32x32 tile transpose. grid: (j-tiles=64, d-tiles=2, bh=32), block (32,8)
__global__ void scale_transpose_v(const u16* __restrict__ w, const int* __restrict__ mask,
                                  u16* __restrict__ Vt) {
  __shared__ u16 tile[32][33];
  const int tx = threadIdx.x, ty = threadIdx.y;
  const int j0 = blockIdx.x * 32, d0 = blockIdx.y * 32;
  const int bh = blockIdx.z, b = bh >> 4, hc = (bh & 15) * 64;
#pragma unroll
  for (int i = 0; i < 32; i += 8) {
    int j = j0 + ty + i;
    u16 v = w[(size_t)(b * 2048 + j) * 1024 + hc + d0 + tx];
    tile[ty + i][tx] = mask[b * 2048 + j] ? (u16)0 : v;
  }
  __syncthreads();
#pragma unroll
  for (int i = 0; i < 32; i += 8)
    Vt[((size_t)bh * 64 + d0 + ty + i) * 2048 + j0 + tx] = tile[tx][ty + i];
}

// ---------------- GEMM: C(MxN) = A(MxK) * BT(NxK)^T  [+bias] --------------
// 128x64 tile / 256 threads / BK=32 (unchanged).
template<bool A_F32, bool OUT_F32>
__launch_bounds__(256)
__global__ void gemm_bt(const void* __restrict__ Ap, const u16* __restrict__ BT,
                        void* __restrict__ Cp, const float* __restrict__ bias,
                        int M, int N, int K) {
  __shared__ __align__(16) u16 As[128 * 32];
  __shared__ __align__(16) u16 Bs[64 * 32];
  const int t = threadIdx.x;
  const int lane = t & 63, wave = t >> 6;
  const int m0 = blockIdx.x * 128, n0 = blockIdx.y * 64;
  const int wm = (wave & 1) * 64, wn = (wave >> 1) * 32;
  const int lrow = lane & 15, quad = lane >> 4;

  f32x4 acc[4][2] = {};

  const int ar = t >> 2, ac = (t & 3) * 8;
  const size_t aBase = (size_t)(m0 + ar) * K + ac;
  const u16* gB = BT + (size_t)(n0 + ar) * K + ac;

  for (int k0 = 0; k0 < K; k0 += 32) {
    uint4 a0, a1;
    if (A_F32) {
      const float* p0 = (const float*)Ap + aBase + k0;
      const float* p1 = (const float*)Ap + aBase + k0 + (size_t)64 * K;
      a0 = pack8(*(const float4*)p0, *(const float4*)(p0 + 4));
      a1 = pack8(*(const float4*)p1, *(const float4*)(p1 + 4));
    } else {
      a0 = *(const uint4*)((const u16*)Ap + aBase + k0);
      a1 = *(const uint4*)((const u16*)Ap + aBase + k0 + (size_t)64 * K);
    }
    uint4 b0 = *(const uint4*)(gB + k0);
    __syncthreads();
    *(uint4*)&As[t * 8]        = a0;
    *(uint4*)&As[t * 8 + 2048] = a1;
    *(uint4*)&Bs[t * 8]        = b0;
    __syncthreads();

    bf16x8 af[4], bfr[2];
#pragma unroll
    for (int i = 0; i < 4; i++)
      af[i] = *(const bf16x8*)&As[(wm + i * 16 + lrow) * 32 + quad * 8];
#pragma unroll
    for (int j = 0; j < 2; j++)
      bfr[j] = *(const bf16x8*)&Bs[(wn + j * 16 + lrow) * 32 + quad * 8];
#pragma unroll
    for (int i = 0; i < 4; i++)
#pragma unroll
      for (int j = 0; j < 2; j++)
        acc[i][j] = __builtin_amdgcn_mfma_f32_16x16x32_bf16(af[i], bfr[j], acc[i][j], 0, 0, 0);
  }

  float bv[2];
#pragma unroll
  for (int j = 0; j < 2; j++)
    bv[j] = bias ? bias[n0 + wn + j * 16 + lrow] : 0.f;

#pragma unroll
  for (int i = 0; i < 4; i++) {
#pragma unroll
    for (int r = 0; r < 4; r++) {
      int row = m0 + wm + i * 16 + quad * 4 + r;
#pragma unroll
      for (int j = 0; j < 2; j++) {
        size_t ci = (size_t)row * N + n0 + wn + j * 16 + lrow;
        float v = acc[i][j][r] + bv[j];
        if (OUT_F32) ((float*)Cp)[ci] = v;
        else ((u16*)Cp)[ci] = f2bf(v);
      }
    }
  }
}

// ---------------- fused attention per (b,h), 64 q-rows per block ----------
// K chunk staged in LDS (Ws, row-major [key][d]); V chunk staged in LDS (VTs,
// [d][key]) from pre-masked pre-transposed Vt — plain coalesced copies, no
// per-chunk transpose/mask work. Single-buffered, register-prefetched one
// chunk ahead, 2 barriers/chunk (m97 pattern). Fixed-max softmax
// e = exp2(fma(z, 0.125*log2e, -20*log2e)); denom over ALL cols (unmasked);
// numerator masking folded into Vt.
#define SV 72
#define C1 0.18033688f      // 0.125 * log2(e)
#define C2 -28.853901f      // -20 * log2(e)
__launch_bounds__(256)
__global__ void attn_kernel(const u16* __restrict__ w, const u16* __restrict__ Vt,
                            u16* __restrict__ y) {
  __shared__ __align__(16) u16 Ws[64 * SV];        // K rows [key][d]
  __shared__ __align__(16) u16 VTs[64 * SV];       // V^T [d][key]
  __shared__ __align__(16) u16 P[4][16 * SV];      // per-wave P: [16 q][64 key]
  const int t = threadIdx.x, lane = t & 63, wave = t >> 6;
  const int lrow = lane & 15, quad = lane >> 4;
  const int bh = blockIdx.y, b = bh >> 4, h = bh & 15;
  const int q0 = blockIdx.x * 64;
  const size_t rowb = (size_t)b * 2048;
  const int hc = h * 64;
  u16* Pw = P[wave];

  const int sr = t >> 2, sc = (t & 3) * 16;  // staging: row sr, 16 elems at sc
  const u16* kg = &w[(rowb + sr) * 1024 + hc + sc];             // += j0*1024
  const u16* vg = &Vt[((size_t)bh * 64 + sr) * 2048 + sc];      // += j0

  // Q fragments: 16 rows x 64 k, in regs for whole kernel
  bf16x8 qf0, qf1;
  {
    const size_t qrow = rowb + q0 + wave * 16 + lrow;
    qf0 = *(const bf16x8*)&w[qrow * 1024 + hc + quad * 8];
    qf1 = *(const bf16x8*)&w[qrow * 1024 + hc + 32 + quad * 8];
  }

  // prefetch chunk 0 into regs
  uint4 ka = *(const uint4*)kg, kb = *(const uint4*)(kg + 8);
  uint4 va = *(const uint4*)vg, vc = *(const uint4*)(vg + 8);

  f32x4 o[4] = {};
  float lrun[4] = {0.f, 0.f, 0.f, 0.f};

  for (int j0 = 0; j0 < 2048; j0 += 64) {
    __syncthreads();                           // prev chunk's LDS reads done
    *(uint4*)&Ws[sr * SV + sc]      = ka;
    *(uint4*)&Ws[sr * SV + sc + 8]  = kb;
    *(uint4*)&VTs[sr * SV + sc]     = va;
    *(uint4*)&VTs[sr * SV + sc + 8] = vc;
    __syncthreads();                           // staging visible

    // ---- prefetch next chunk (full compute phase to land)
    if (j0 + 64 < 2048) {
      const u16* kn = kg + (size_t)(j0 + 64) * 1024;
      const u16* vn = vg + j0 + 64;
      ka = *(const uint4*)kn; kb = *(const uint4*)(kn + 8);
      va = *(const uint4*)vn; vc = *(const uint4*)(vn + 8);
    }

    // ---- QK^T from LDS K tile
    f32x4 st[4];
#pragma unroll
    for (int jt = 0; jt < 4; jt++) {
      bf16x8 kf0 = *(const bf16x8*)&Ws[(jt * 16 + lrow) * SV + quad * 8];
      bf16x8 kf1 = *(const bf16x8*)&Ws[(jt * 16 + lrow) * SV + 32 + quad * 8];
      f32x4 z = {};
      z = __builtin_amdgcn_mfma_f32_16x16x32_bf16(qf0, kf0, z, 0, 0, 0);
      z = __builtin_amdgcn_mfma_f32_16x16x32_bf16(qf1, kf1, z, 0, 0, 0);
      st[jt] = z;
    }

    // ---- softmax (fixed max, folded scale); masking lives in Vt
#pragma unroll
    for (int jt = 0; jt < 4; jt++) {
#pragma unroll
      for (int r = 0; r < 4; r++) {
        float e = exp2f(fmaf(st[jt][r], C1, C2));
        lrun[r] += e;                           // denominator: UNmasked
        Pw[(quad * 4 + r) * SV + jt * 16 + lrow] = f2bf(e);
      }
    }

    // ---- P·V from LDS (P same-wave round-trip; V pre-masked)
    bf16x8 pa0 = *(const bf16x8*)&Pw[lrow * SV + quad * 8];
    bf16x8 pa1 = *(const bf16x8*)&Pw[lrow * SV + 32 + quad * 8];
#pragma unroll
    for (int dt = 0; dt < 4; dt++) {
      bf16x8 vb0 = *(const bf16x8*)&VTs[(dt * 16 + lrow) * SV + quad * 8];
      bf16x8 vb1 = *(const bf16x8*)&VTs[(dt * 16 + lrow) * SV + 32 + quad * 8];
      o[dt] = __builtin_amdgcn_mfma_f32_16x16x32_bf16(pa0, vb0, o[dt], 0, 0, 0);
      o[dt] = __builtin_amdgcn_mfma_f32_16x16x32_bf16(pa1, vb1, o[dt], 0, 0, 0);
    }
  }

  // ---- finalize: reduce denominator across 16-lane group, divide, store
#pragma unroll
  for (int r = 0; r < 4; r++) {
    float l = lrun[r];
#pragma unroll
    for (int s = 8; s >= 1; s >>= 1)
      l += __shfl_xor(l, s, 64);
    float inv = 1.f / l;
    const size_t orow = rowb + q0 + wave * 16 + quad * 4 + r;
#pragma unroll
    for (int dt = 0; dt < 4; dt++)
      y[orow * 1024 + hc + dt * 16 + lrow] = f2bf(o[dt][r] * inv);
  }
}

// --------------------------------------------------------------------------
extern "C" void kernel_launch(void* const* d_in, const int* in_sizes, int n_in,
                              void* d_out, int out_size, void* d_ws, size_t ws_size,
                              hipStream_t stream) {
  const float* x    = (const float*)d_in[0];  // (2,2048,1024) fp32
  const int* mask   = (const int*)d_in[1];    // (2,2048) int32
  const float* Wqkv = (const float*)d_in[2];  // (1024,1024) fp32
  const float* Wout = (const float*)d_in[3];  // (1024,1024) fp32
  const float* bout = (const float*)d_in[4];  // (1024,) fp32
  float* out = (float*)d_out;                 // (2,2048,1024) fp32

  u16* w     = (u16*)d_ws;                 // 4096*1024 bf16   (8 MB)
  u16* y     = w + 4096 * 1024;            // 4096*1024 bf16   (8 MB)
  u16* WqkvT = y + 4096 * 1024;            // 1024*1024 bf16   (2 MB)
  u16* WoutT = WqkvT + 1024 * 1024;        // 1024*1024 bf16   (2 MB)
  u16* Vt    = WoutT + 1024 * 1024;        // 32*64*2048 bf16  (8 MB)

  transpose1024_cvt2<<<dim3(32, 32, 2), dim3(32, 8), 0, stream>>>(Wqkv, WqkvT, Wout, WoutT);
  gemm_bt<true, false><<<dim3(32, 16), 256, 0, stream>>>(x, WqkvT, w, nullptr, 4096, 1024, 1024);
  scale_transpose_v<<<dim3(64, 2, 32), dim3(32, 8), 0, stream>>>(w, mask, Vt);
  attn_kernel<<<dim3(32, 32), 256, 0, stream>>>(w, Vt, y);
  gemm_bt<false, true><<<dim3(32, 16), 256, 0, stream>>>(y, WoutT, out, bout, 4096, 1024, 1024);
}

// Round 9
// 197.449 us; speedup vs baseline: 1.8080x; 1.0326x over previous
//
#include <hip/hip_runtime.h>
#include <hip/hip_bf16.h>
#include <stdint.h>

typedef unsigned short u16;
typedef unsigned int u32;
typedef __bf16 bf16x8 __attribute__((ext_vector_type(8)));
typedef float f32x4 __attribute__((ext_vector_type(4)));

#define AS1 __attribute__((address_space(1)))
#define AS3 __attribute__((address_space(3)))

// async global->LDS, 16B per lane; LDS dest = wave-uniform base + lane*16.
__device__ __forceinline__ void async16(const u16* g, u16* l) {
  __builtin_amdgcn_global_load_lds((const AS1 uint32_t*)(const void*)g,
                                   (AS3 uint32_t*)l, 16, 0, 0);
}

__device__ __forceinline__ u16 f2bf(float v) {
  union { __hip_bfloat16 b; u16 u; } c; c.b = __float2bfloat16(v); return c.u;
}

__device__ __forceinline__ uint4 pack8(float4 lo, float4 hi) {
  uint4 q;
  q.x = (u32)f2bf(lo.x) | ((u32)f2bf(lo.y) << 16);
  q.y = (u32)f2bf(lo.z) | ((u32)f2bf(lo.w) << 16);
  q.z = (u32)f2bf(hi.x) | ((u32)f2bf(hi.y) << 16);
  q.w = (u32)f2bf(hi.z) | ((u32)f2bf(hi.w) << 16);
  return q;
}

// ---------------- x: fp32 -> bf16, 4M elems ------------------------------
__global__ void cvt_x(const float* __restrict__ in, u16* __restrict__ out) {
  int i = (blockIdx.x * 256 + threadIdx.x) * 8;     // grid covers 4M/8
  float4 lo = *(const float4*)(in + i);
  float4 hi = *(const float4*)(in + i + 4);
  *(uint4*)(out + i) = pack8(lo, hi);
}

// ---------------- transpose + fp32->bf16 convert, 2x 1024x1024 ------------
__global__ void transpose1024_cvt2(const float* __restrict__ in0, u16* __restrict__ out0,
                                   const float* __restrict__ in1, u16* __restrict__ out1) {
  const float* in = blockIdx.z ? in1 : in0;
  u16* out = blockIdx.z ? out1 : out0;
  __shared__ u16 tile[32][33];
  int tx = threadIdx.x, ty = threadIdx.y;            // block (32,8)
  int c0 = blockIdx.x * 32, r0 = blockIdx.y * 32;
#pragma unroll
  for (int i = 0; i < 32; i += 8)
    tile[ty + i][tx] = f2bf(in[(size_t)(r0 + ty + i) * 1024 + c0 + tx]);
  __syncthreads();
#pragma unroll
  for (int i = 0; i < 32; i += 8)
    out[(size_t)(c0 + ty + i) * 1024 + r0 + tx] = tile[tx][ty + i];
}

// ---------------- build Vt[b][h][d][j] = mask[b][j] ? 0 : w[b,j][h*64+d] --
__global__ void scale_transpose_v(const u16* __restrict__ w, const int* __restrict__ mask,
                                  u16* __restrict__ Vt) {
  __shared__ u16 tile[32][33];
  const int tx = threadIdx.x, ty = threadIdx.y;
  const int j0 = blockIdx.x * 32, d0 = blockIdx.y * 32;
  const int bh = blockIdx.z, b = bh >> 4, hc = (bh & 15) * 64;
#pragma unroll
  for (int i = 0; i < 32; i += 8) {
    int j = j0 + ty + i;
    u16 v = w[(size_t)(b * 2048 + j) * 1024 + hc + d0 + tx];
    tile[ty + i][tx] = mask[b * 2048 + j] ? (u16)0 : v;
  }
  __syncthreads();
#pragma unroll
  for (int i = 0; i < 32; i += 8)
    Vt[((size_t)bh * 64 + d0 + ty + i) * 2048 + j0 + tx] = tile[tx][ty + i];
}

// ---------------- GEMM: C(MxN) = A(MxK) * BT(NxK)^T  [+bias], bf16 A/B ----
// 128x64 tile / 256 threads / BK=32, m97-style global_load_lds width-16.
template<bool OUT_F32>
__launch_bounds__(256)
__global__ void gemm_bt(const u16* __restrict__ A, const u16* __restrict__ BT,
                        void* __restrict__ Cp, const float* __restrict__ bias,
                        int M, int N, int K) {
  __shared__ __align__(16) u16 As[128 * 32];
  __shared__ __align__(16) u16 Bs[64 * 32];
  const int t = threadIdx.x;
  const int lane = t & 63, wave = t >> 6;
  const int m0 = blockIdx.x * 128, n0 = blockIdx.y * 64;
  const int wm = (wave & 1) * 64, wn = (wave >> 1) * 32;
  const int lrow = lane & 15, quad = lane >> 4;

  f32x4 acc[4][2] = {};

  const int ar = t >> 2, ac = (t & 3) * 8;     // staging: row t/4, 16B-chunk t%4
  const u16* gA = A + (size_t)(m0 + ar) * K + ac;
  const u16* gB = BT + (size_t)(n0 + ar) * K + ac;

  for (int k0 = 0; k0 < K; k0 += 32) {
    async16(gA + k0,                  &As[t * 8]);
    async16(gA + k0 + (size_t)64 * K, &As[t * 8 + 2048]);
    async16(gB + k0,                  &Bs[t * 8]);
    __syncthreads();                           // drains vmcnt + barrier

    bf16x8 af[4], bfr[2];
#pragma unroll
    for (int i = 0; i < 4; i++)
      af[i] = *(const bf16x8*)&As[(wm + i * 16 + lrow) * 32 + quad * 8];
#pragma unroll
    for (int j = 0; j < 2; j++)
      bfr[j] = *(const bf16x8*)&Bs[(wn + j * 16 + lrow) * 32 + quad * 8];
#pragma unroll
    for (int i = 0; i < 4; i++)
#pragma unroll
      for (int j = 0; j < 2; j++)
        acc[i][j] = __builtin_amdgcn_mfma_f32_16x16x32_bf16(af[i], bfr[j], acc[i][j], 0, 0, 0);
    __syncthreads();                           // LDS reads done before restage
  }

  float bv[2];
#pragma unroll
  for (int j = 0; j < 2; j++)
    bv[j] = bias ? bias[n0 + wn + j * 16 + lrow] : 0.f;

#pragma unroll
  for (int i = 0; i < 4; i++) {
#pragma unroll
    for (int r = 0; r < 4; r++) {
      int row = m0 + wm + i * 16 + quad * 4 + r;
#pragma unroll
      for (int j = 0; j < 2; j++) {
        size_t ci = (size_t)row * N + n0 + wn + j * 16 + lrow;
        float v = acc[i][j][r] + bv[j];
        if (OUT_F32) ((float*)Cp)[ci] = v;
        else ((u16*)Cp)[ci] = f2bf(v);
      }
    }
  }
}

// ---------------- fused attention per (b,h), 64 q-rows per block ----------
// (unchanged round-8 winner) K staged in LDS; V staged from pre-masked,
// pre-transposed Vt; single-buffered + register prefetch; fixed-max softmax.
#define SV 72
#define C1 0.18033688f      // 0.125 * log2(e)
#define C2 -28.853901f      // -20 * log2(e)
__launch_bounds__(256)
__global__ void attn_kernel(const u16* __restrict__ w, const u16* __restrict__ Vt,
                            u16* __restrict__ y) {
  __shared__ __align__(16) u16 Ws[64 * SV];        // K rows [key][d]
  __shared__ __align__(16) u16 VTs[64 * SV];       // V^T [d][key]
  __shared__ __align__(16) u16 P[4][16 * SV];      // per-wave P: [16 q][64 key]
  const int t = threadIdx.x, lane = t & 63, wave = t >> 6;
  const int lrow = lane & 15, quad = lane >> 4;
  const int bh = blockIdx.y, b = bh >> 4, h = bh & 15;
  const int q0 = blockIdx.x * 64;
  const size_t rowb = (size_t)b * 2048;
  const int hc = h * 64;
  u16* Pw = P[wave];

  const int sr = t >> 2, sc = (t & 3) * 16;
  const u16* kg = &w[(rowb + sr) * 1024 + hc + sc];
  const u16* vg = &Vt[((size_t)bh * 64 + sr) * 2048 + sc];

  bf16x8 qf0, qf1;
  {
    const size_t qrow = rowb + q0 + wave * 16 + lrow;
    qf0 = *(const bf16x8*)&w[qrow * 1024 + hc + quad * 8];
    qf1 = *(const bf16x8*)&w[qrow * 1024 + hc + 32 + quad * 8];
  }

  uint4 ka = *(const uint4*)kg, kb = *(const uint4*)(kg + 8);
  uint4 va = *(const uint4*)vg, vc = *(const uint4*)(vg + 8);

  f32x4 o[4] = {};
  float lrun[4] = {0.f, 0.f, 0.f, 0.f};

  for (int j0 = 0; j0 < 2048; j0 += 64) {
    __syncthreads();
    *(uint4*)&Ws[sr * SV + sc]      = ka;
    *(uint4*)&Ws[sr * SV + sc + 8]  = kb;
    *(uint4*)&VTs[sr * SV + sc]     = va;
    *(uint4*)&VTs[sr * SV + sc + 8] = vc;
    __syncthreads();

    if (j0 + 64 < 2048) {
      const u16* kn = kg + (size_t)(j0 + 64) * 1024;
      const u16* vn = vg + j0 + 64;
      ka = *(const uint4*)kn; kb = *(const uint4*)(kn + 8);
      va = *(const uint4*)vn; vc = *(const uint4*)(vn + 8);
    }

    f32x4 st[4];
#pragma unroll
    for (int jt = 0; jt < 4; jt++) {
      bf16x8 kf0 = *(const bf16x8*)&Ws[(jt * 16 + lrow) * SV + quad * 8];
      bf16x8 kf1 = *(const bf16x8*)&Ws[(jt * 16 + lrow) * SV + 32 + quad * 8];
      f32x4 z = {};
      z = __builtin_amdgcn_mfma_f32_16x16x32_bf16(qf0, kf0, z, 0, 0, 0);
      z = __builtin_amdgcn_mfma_f32_16x16x32_bf16(qf1, kf1, z, 0, 0, 0);
      st[jt] = z;
    }

#pragma unroll
    for (int jt = 0; jt < 4; jt++) {
#pragma unroll
      for (int r = 0; r < 4; r++) {
        float e = exp2f(fmaf(st[jt][r], C1, C2));
        lrun[r] += e;                           // denominator: UNmasked
        Pw[(quad * 4 + r) * SV + jt * 16 + lrow] = f2bf(e);
      }
    }

    bf16x8 pa0 = *(const bf16x8*)&Pw[lrow * SV + quad * 8];
    bf16x8 pa1 = *(const bf16x8*)&Pw[lrow * SV + 32 + quad * 8];
#pragma unroll
    for (int dt = 0; dt < 4; dt++) {
      bf16x8 vb0 = *(const bf16x8*)&VTs[(dt * 16 + lrow) * SV + quad * 8];
      bf16x8 vb1 = *(const bf16x8*)&VTs[(dt * 16 + lrow) * SV + 32 + quad * 8];
      o[dt] = __builtin_amdgcn_mfma_f32_16x16x32_bf16(pa0, vb0, o[dt], 0, 0, 0);
      o[dt] = __builtin_amdgcn_mfma_f32_16x16x32_bf16(pa1, vb1, o[dt], 0, 0, 0);
    }
  }

#pragma unroll
  for (int r = 0; r < 4; r++) {
    float l = lrun[r];
#pragma unroll
    for (int s = 8; s >= 1; s >>= 1)
      l += __shfl_xor(l, s, 64);
    float inv = 1.f / l;
    const size_t orow = rowb + q0 + wave * 16 + quad * 4 + r;
#pragma unroll
    for (int dt = 0; dt < 4; dt++)
      y[orow * 1024 + hc + dt * 16 + lrow] = f2bf(o[dt][r] * inv);
  }
}

// --------------------------------------------------------------------------
extern "C" void kernel_launch(void* const* d_in, const int* in_sizes, int n_in,
                              void* d_out, int out_size, void* d_ws, size_t ws_size,
                              hipStream_t stream) {
  const float* x    = (const float*)d_in[0];  // (2,2048,1024) fp32
  const int* mask   = (const int*)d_in[1];    // (2,2048) int32
  const float* Wqkv = (const float*)d_in[2];  // (1024,1024) fp32
  const float* Wout = (const float*)d_in[3];  // (1024,1024) fp32
  const float* bout = (const float*)d_in[4];  // (1024,) fp32
  float* out = (float*)d_out;                 // (2,2048,1024) fp32

  u16* w     = (u16*)d_ws;                 // 4096*1024 bf16   (8 MB)
  u16* y     = w + 4096 * 1024;            // 4096*1024 bf16   (8 MB)
  u16* WqkvT = y + 4096 * 1024;            // 1024*1024 bf16   (2 MB)
  u16* WoutT = WqkvT + 1024 * 1024;        // 1024*1024 bf16   (2 MB)
  u16* Vt    = WoutT + 1024 * 1024;        // 32*64*2048 bf16  (8 MB)
  u16* xb    = y;                          // alias: y dead until attn writes it

  cvt_x<<<2048, 256, 0, stream>>>(x, xb);
  transpose1024_cvt2<<<dim3(32, 32, 2), dim3(32, 8), 0, stream>>>(Wqkv, WqkvT, Wout, WoutT);
  gemm_bt<false><<<dim3(32, 16), 256, 0, stream>>>(xb, WqkvT, w, nullptr, 4096, 1024, 1024);
  scale_transpose_v<<<dim3(64, 2, 32), dim3(32, 8), 0, stream>>>(w, mask, Vt);
  attn_kernel<<<dim3(32, 32), 256, 0, stream>>>(w, Vt, y);
  gemm_bt<true><<<dim3(32, 16), 256, 0, stream>>>(y, WoutT, out, bout, 4096, 1024, 1024);
}

// Round 10
// 193.566 us; speedup vs baseline: 1.8443x; 1.0201x over previous
//
#include <hip/hip_runtime.h>
#include <hip/hip_bf16.h>
#include <stdint.h>

typedef unsigned short u16;
typedef unsigned int u32;
typedef __bf16 bf16x8 __attribute__((ext_vector_type(8)));
typedef float f32x4 __attribute__((ext_vector_type(4)));

#define AS1 __attribute__((address_space(1)))
#define AS3 __attribute__((address_space(3)))

// async global->LDS, 16B per lane; LDS dest = wave-uniform base + lane*16.
__device__ __forceinline__ void async16(const u16* g, u16* l) {
  __builtin_amdgcn_global_load_lds((const AS1 uint32_t*)(const void*)g,
                                   (AS3 uint32_t*)l, 16, 0, 0);
}

__device__ __forceinline__ u16 f2bf(float v) {
  union { __hip_bfloat16 b; u16 u; } c; c.b = __float2bfloat16(v); return c.u;
}

__device__ __forceinline__ uint4 pack8(float4 lo, float4 hi) {
  uint4 q;
  q.x = (u32)f2bf(lo.x) | ((u32)f2bf(lo.y) << 16);
  q.y = (u32)f2bf(lo.z) | ((u32)f2bf(lo.w) << 16);
  q.z = (u32)f2bf(hi.x) | ((u32)f2bf(hi.y) << 16);
  q.w = (u32)f2bf(hi.z) | ((u32)f2bf(hi.w) << 16);
  return q;
}

// ---------------- x: fp32 -> bf16, 4M elems ------------------------------
__global__ void cvt_x(const float* __restrict__ in, u16* __restrict__ out) {
  int i = (blockIdx.x * 256 + threadIdx.x) * 8;     // grid covers 4M/8
  float4 lo = *(const float4*)(in + i);
  float4 hi = *(const float4*)(in + i + 4);
  *(uint4*)(out + i) = pack8(lo, hi);
}

// ---------------- transpose + fp32->bf16 convert, 2x 1024x1024 ------------
__global__ void transpose1024_cvt2(const float* __restrict__ in0, u16* __restrict__ out0,
                                   const float* __restrict__ in1, u16* __restrict__ out1) {
  const float* in = blockIdx.z ? in1 : in0;
  u16* out = blockIdx.z ? out1 : out0;
  __shared__ u16 tile[32][33];
  int tx = threadIdx.x, ty = threadIdx.y;            // block (32,8)
  int c0 = blockIdx.x * 32, r0 = blockIdx.y * 32;
#pragma unroll
  for (int i = 0; i < 32; i += 8)
    tile[ty + i][tx] = f2bf(in[(size_t)(r0 + ty + i) * 1024 + c0 + tx]);
  __syncthreads();
#pragma unroll
  for (int i = 0; i < 32; i += 8)
    out[(size_t)(c0 + ty + i) * 1024 + r0 + tx] = tile[tx][ty + i];
}

// ---------------- build Vt[b][h][d][j] = mask[b][j] ? 0 : w[b,j][h*64+d] --
__global__ void scale_transpose_v(const u16* __restrict__ w, const int* __restrict__ mask,
                                  u16* __restrict__ Vt) {
  __shared__ u16 tile[32][33];
  const int tx = threadIdx.x, ty = threadIdx.y;
  const int j0 = blockIdx.x * 32, d0 = blockIdx.y * 32;
  const int bh = blockIdx.z, b = bh >> 4, hc = (bh & 15) * 64;
#pragma unroll
  for (int i = 0; i < 32; i += 8) {
    int j = j0 + ty + i;
    u16 v = w[(size_t)(b * 2048 + j) * 1024 + hc + d0 + tx];
    tile[ty + i][tx] = mask[b * 2048 + j] ? (u16)0 : v;
  }
  __syncthreads();
#pragma unroll
  for (int i = 0; i < 32; i += 8)
    Vt[((size_t)bh * 64 + d0 + ty + i) * 2048 + j0 + tx] = tile[tx][ty + i];
}

// ---------------- GEMM: C(MxN) = A(MxK) * BT(NxK)^T  [+bias], bf16 A/B ----
// 128x64 tile / 256 threads / BK=64 stored as two BK=32 sub-tiles.
// 6 async16 + 16 MFMA/wave per barrier-pair; 16 iters (half the drains).
template<bool OUT_F32>
__launch_bounds__(256)
__global__ void gemm_bt(const u16* __restrict__ A, const u16* __restrict__ BT,
                        void* __restrict__ Cp, const float* __restrict__ bias,
                        int M, int N, int K) {
  __shared__ __align__(16) u16 As[2][128 * 32];
  __shared__ __align__(16) u16 Bs[2][64 * 32];
  const int t = threadIdx.x;
  const int lane = t & 63, wave = t >> 6;
  const int m0 = blockIdx.x * 128, n0 = blockIdx.y * 64;
  const int wm = (wave & 1) * 64, wn = (wave >> 1) * 32;
  const int lrow = lane & 15, quad = lane >> 4;

  f32x4 acc[4][2] = {};

  const int ar = t >> 2, ac = (t & 3) * 8;     // staging: row t/4, 16B-chunk t%4
  const u16* gA = A + (size_t)(m0 + ar) * K + ac;
  const u16* gB = BT + (size_t)(n0 + ar) * K + ac;

  for (int k0 = 0; k0 < K; k0 += 64) {
    async16(gA + k0,                       &As[0][t * 8]);
    async16(gA + k0 + (size_t)64 * K,      &As[0][t * 8 + 2048]);
    async16(gA + k0 + 32,                  &As[1][t * 8]);
    async16(gA + k0 + 32 + (size_t)64 * K, &As[1][t * 8 + 2048]);
    async16(gB + k0,                       &Bs[0][t * 8]);
    async16(gB + k0 + 32,                  &Bs[1][t * 8]);
    __syncthreads();                           // drains vmcnt + barrier

#pragma unroll
    for (int kk = 0; kk < 2; kk++) {
      bf16x8 af[4], bfr[2];
#pragma unroll
      for (int i = 0; i < 4; i++)
        af[i] = *(const bf16x8*)&As[kk][(wm + i * 16 + lrow) * 32 + quad * 8];
#pragma unroll
      for (int j = 0; j < 2; j++)
        bfr[j] = *(const bf16x8*)&Bs[kk][(wn + j * 16 + lrow) * 32 + quad * 8];
#pragma unroll
      for (int i = 0; i < 4; i++)
#pragma unroll
        for (int j = 0; j < 2; j++)
          acc[i][j] = __builtin_amdgcn_mfma_f32_16x16x32_bf16(af[i], bfr[j], acc[i][j], 0, 0, 0);
    }
    __syncthreads();                           // LDS reads done before restage
  }

  float bv[2];
#pragma unroll
  for (int j = 0; j < 2; j++)
    bv[j] = bias ? bias[n0 + wn + j * 16 + lrow] : 0.f;

#pragma unroll
  for (int i = 0; i < 4; i++) {
#pragma unroll
    for (int r = 0; r < 4; r++) {
      int row = m0 + wm + i * 16 + quad * 4 + r;
#pragma unroll
      for (int j = 0; j < 2; j++) {
        size_t ci = (size_t)row * N + n0 + wn + j * 16 + lrow;
        float v = acc[i][j][r] + bv[j];
        if (OUT_F32) ((float*)Cp)[ci] = v;
        else ((u16*)Cp)[ci] = f2bf(v);
      }
    }
  }
}

// ---------------- fused attention per (b,h), 64 q-rows per block ----------
// (unchanged round-8 winner)
#define SV 72
#define C1 0.18033688f      // 0.125 * log2(e)
#define C2 -28.853901f      // -20 * log2(e)
__launch_bounds__(256)
__global__ void attn_kernel(const u16* __restrict__ w, const u16* __restrict__ Vt,
                            u16* __restrict__ y) {
  __shared__ __align__(16) u16 Ws[64 * SV];        // K rows [key][d]
  __shared__ __align__(16) u16 VTs[64 * SV];       // V^T [d][key]
  __shared__ __align__(16) u16 P[4][16 * SV];      // per-wave P: [16 q][64 key]
  const int t = threadIdx.x, lane = t & 63, wave = t >> 6;
  const int lrow = lane & 15, quad = lane >> 4;
  const int bh = blockIdx.y, b = bh >> 4, h = bh & 15;
  const int q0 = blockIdx.x * 64;
  const size_t rowb = (size_t)b * 2048;
  const int hc = h * 64;
  u16* Pw = P[wave];

  const int sr = t >> 2, sc = (t & 3) * 16;
  const u16* kg = &w[(rowb + sr) * 1024 + hc + sc];
  const u16* vg = &Vt[((size_t)bh * 64 + sr) * 2048 + sc];

  bf16x8 qf0, qf1;
  {
    const size_t qrow = rowb + q0 + wave * 16 + lrow;
    qf0 = *(const bf16x8*)&w[qrow * 1024 + hc + quad * 8];
    qf1 = *(const bf16x8*)&w[qrow * 1024 + hc + 32 + quad * 8];
  }

  uint4 ka = *(const uint4*)kg, kb = *(const uint4*)(kg + 8);
  uint4 va = *(const uint4*)vg, vc = *(const uint4*)(vg + 8);

  f32x4 o[4] = {};
  float lrun[4] = {0.f, 0.f, 0.f, 0.f};

  for (int j0 = 0; j0 < 2048; j0 += 64) {
    __syncthreads();
    *(uint4*)&Ws[sr * SV + sc]      = ka;
    *(uint4*)&Ws[sr * SV + sc + 8]  = kb;
    *(uint4*)&VTs[sr * SV + sc]     = va;
    *(uint4*)&VTs[sr * SV + sc + 8] = vc;
    __syncthreads();

    if (j0 + 64 < 2048) {
      const u16* kn = kg + (size_t)(j0 + 64) * 1024;
      const u16* vn = vg + j0 + 64;
      ka = *(const uint4*)kn; kb = *(const uint4*)(kn + 8);
      va = *(const uint4*)vn; vc = *(const uint4*)(vn + 8);
    }

    f32x4 st[4];
#pragma unroll
    for (int jt = 0; jt < 4; jt++) {
      bf16x8 kf0 = *(const bf16x8*)&Ws[(jt * 16 + lrow) * SV + quad * 8];
      bf16x8 kf1 = *(const bf16x8*)&Ws[(jt * 16 + lrow) * SV + 32 + quad * 8];
      f32x4 z = {};
      z = __builtin_amdgcn_mfma_f32_16x16x32_bf16(qf0, kf0, z, 0, 0, 0);
      z = __builtin_amdgcn_mfma_f32_16x16x32_bf16(qf1, kf1, z, 0, 0, 0);
      st[jt] = z;
    }

#pragma unroll
    for (int jt = 0; jt < 4; jt++) {
#pragma unroll
      for (int r = 0; r < 4; r++) {
        float e = exp2f(fmaf(st[jt][r], C1, C2));
        lrun[r] += e;                           // denominator: UNmasked
        Pw[(quad * 4 + r) * SV + jt * 16 + lrow] = f2bf(e);
      }
    }

    bf16x8 pa0 = *(const bf16x8*)&Pw[lrow * SV + quad * 8];
    bf16x8 pa1 = *(const bf16x8*)&Pw[lrow * SV + 32 + quad * 8];
#pragma unroll
    for (int dt = 0; dt < 4; dt++) {
      bf16x8 vb0 = *(const bf16x8*)&VTs[(dt * 16 + lrow) * SV + quad * 8];
      bf16x8 vb1 = *(const bf16x8*)&VTs[(dt * 16 + lrow) * SV + 32 + quad * 8];
      o[dt] = __builtin_amdgcn_mfma_f32_16x16x32_bf16(pa0, vb0, o[dt], 0, 0, 0);
      o[dt] = __builtin_amdgcn_mfma_f32_16x16x32_bf16(pa1, vb1, o[dt], 0, 0, 0);
    }
  }

#pragma unroll
  for (int r = 0; r < 4; r++) {
    float l = lrun[r];
#pragma unroll
    for (int s = 8; s >= 1; s >>= 1)
      l += __shfl_xor(l, s, 64);
    float inv = 1.f / l;
    const size_t orow = rowb + q0 + wave * 16 + quad * 4 + r;
#pragma unroll
    for (int dt = 0; dt < 4; dt++)
      y[orow * 1024 + hc + dt * 16 + lrow] = f2bf(o[dt][r] * inv);
  }
}

// --------------------------------------------------------------------------
extern "C" void kernel_launch(void* const* d_in, const int* in_sizes, int n_in,
                              void* d_out, int out_size, void* d_ws, size_t ws_size,
                              hipStream_t stream) {
  const float* x    = (const float*)d_in[0];  // (2,2048,1024) fp32
  const int* mask   = (const int*)d_in[1];    // (2,2048) int32
  const float* Wqkv = (const float*)d_in[2];  // (1024,1024) fp32
  const float* Wout = (const float*)d_in[3];  // (1024,1024) fp32
  const float* bout = (const float*)d_in[4];  // (1024,) fp32
  float* out = (float*)d_out;                 // (2,2048,1024) fp32

  u16* w     = (u16*)d_ws;                 // 4096*1024 bf16   (8 MB)
  u16* y     = w + 4096 * 1024;            // 4096*1024 bf16   (8 MB)
  u16* WqkvT = y + 4096 * 1024;            // 1024*1024 bf16   (2 MB)
  u16* WoutT = WqkvT + 1024 * 1024;        // 1024*1024 bf16   (2 MB)
  u16* Vt    = WoutT + 1024 * 1024;        // 32*64*2048 bf16  (8 MB)
  u16* xb    = y;                          // alias: y dead until attn writes it

  cvt_x<<<2048, 256, 0, stream>>>(x, xb);
  transpose1024_cvt2<<<dim3(32, 32, 2), dim3(32, 8), 0, stream>>>(Wqkv, WqkvT, Wout, WoutT);
  gemm_bt<false><<<dim3(32, 16), 256, 0, stream>>>(xb, WqkvT, w, nullptr, 4096, 1024, 1024);
  scale_transpose_v<<<dim3(64, 2, 32), dim3(32, 8), 0, stream>>>(w, mask, Vt);
  attn_kernel<<<dim3(32, 32), 256, 0, stream>>>(w, Vt, y);
  gemm_bt<true><<<dim3(32, 16), 256, 0, stream>>>(y, WoutT, out, bout, 4096, 1024, 1024);
}